// Round 1
// baseline (998.332 us; speedup 1.0000x reference)
//
#include <hip/hip_runtime.h>
#include <hip/hip_bf16.h>
#include <stdint.h>

// EPLB router: LN -> [router MLP H->H->64  +  balance MLP H->1024->64] -> softmax/top2/EMA
// Strategy: f16 split-precision (hi + lo*2^-11, lo scaled into normal range) MFMA GEMMs,
// fused W1c=[w1|lw1] (N=3072) and W2c=[w2;0.01*lw2] (K=3072,N=64), fp32-class accuracy.

#define TOKENS 16384
#define CHUNK  8192
#define HDIM   2048
#define N1     3072
#define NEXP   64
#define LO_SCALE 2048.0f
#define INV_LO_SCALE (1.0f/2048.0f)

typedef _Float16 half8 __attribute__((ext_vector_type(8)));
typedef float f32x4 __attribute__((ext_vector_type(4)));

__device__ __forceinline__ void gl_lds16(const void* g, void* l) {
  __builtin_amdgcn_global_load_lds((__attribute__((address_space(1))) void*)(g),
                                   (__attribute__((address_space(3))) void*)(l),
                                   16, 0, 0);
}

__device__ __forceinline__ f32x4 mfma16(half8 a, half8 b, f32x4 c) {
  return __builtin_amdgcn_mfma_f32_16x16x32_f16(a, b, c, 0, 0, 0);
}

__device__ __forceinline__ void split_f32(float v, _Float16& hi, _Float16& lo) {
  hi = (_Float16)v;
  lo = (_Float16)((v - (float)hi) * LO_SCALE);
}

// ---------------- weight transpose + split: dst[(c+row_off)*dst_ld + (r+col_off)] = split(src[r][c]*scale)
__global__ __launch_bounds__(256) void transpose_split_k(
    const float* __restrict__ src, int R, int C, int src_ld,
    _Float16* __restrict__ dst_hi, _Float16* __restrict__ dst_lo,
    int dst_ld, int row_off, int col_off, float scale)
{
  __shared__ float tile[32][33];
  const int tx = threadIdx.x & 31, ty = threadIdx.x >> 5;
  const int r0 = blockIdx.x * 32, c0 = blockIdx.y * 32;
#pragma unroll
  for (int i = 0; i < 4; i++)
    tile[ty + i*8][tx] = src[(size_t)(r0 + ty + i*8) * src_ld + c0 + tx];
  __syncthreads();
#pragma unroll
  for (int i = 0; i < 4; i++) {
    const int c = c0 + ty + i*8;
    const int r = r0 + tx;
    const float v = tile[tx][ty + i*8] * scale;
    _Float16 h, l;
    split_f32(v, h, l);
    const size_t o = (size_t)(c + row_off) * dst_ld + (r + col_off);
    dst_hi[o] = h; dst_lo[o] = l;
  }
}

__global__ void prep_bias_k(const float* __restrict__ b1, const float* __restrict__ lb1,
                            const float* __restrict__ b2, const float* __restrict__ lb2,
                            float* __restrict__ b1c, float* __restrict__ b2c)
{
  const int i = blockIdx.x * 256 + threadIdx.x;
  if (i < 2048)      b1c[i] = b1[i];
  else if (i < 3072) b1c[i] = lb1[i - 2048];
  else if (i < 3136) { const int e = i - 3072; b2c[e] = b2[e] + 0.01f * lb2[e]; }
}

// ---------------- LayerNorm + f16 hi/lo split store
__global__ __launch_bounds__(256) void ln_split_k(
    const float* __restrict__ x, const float* __restrict__ gamma, const float* __restrict__ beta,
    _Float16* __restrict__ xh, _Float16* __restrict__ xl)
{
  const int row = blockIdx.x, tid = threadIdx.x, l = tid & 63, w = tid >> 6;
  const float* xr = x + (size_t)row * HDIM;
  const float4 v0 = ((const float4*)xr)[tid*2];
  const float4 v1 = ((const float4*)xr)[tid*2 + 1];
  float vv[8] = {v0.x, v0.y, v0.z, v0.w, v1.x, v1.y, v1.z, v1.w};
  float s = 0.0f;
#pragma unroll
  for (int j = 0; j < 8; j++) s += vv[j];
  for (int off = 1; off < 64; off <<= 1) s += __shfl_xor(s, off);
  __shared__ float r1[4], r2[4];
  if (l == 0) r1[w] = s;
  __syncthreads();
  const float mu = (r1[0] + r1[1] + r1[2] + r1[3]) * (1.0f / HDIM);
  float q = 0.0f;
#pragma unroll
  for (int j = 0; j < 8; j++) { const float d = vv[j] - mu; q += d * d; }
  for (int off = 1; off < 64; off <<= 1) q += __shfl_xor(q, off);
  if (l == 0) r2[w] = q;
  __syncthreads();
  const float var = (r2[0] + r2[1] + r2[2] + r2[3]) * (1.0f / HDIM);
  const float rsig = 1.0f / sqrtf(var + 1e-5f);
  const float4 g0 = ((const float4*)gamma)[tid*2];
  const float4 g1 = ((const float4*)gamma)[tid*2 + 1];
  const float4 be0 = ((const float4*)beta)[tid*2];
  const float4 be1 = ((const float4*)beta)[tid*2 + 1];
  const float gg[8] = {g0.x,g0.y,g0.z,g0.w,g1.x,g1.y,g1.z,g1.w};
  const float bb[8] = {be0.x,be0.y,be0.z,be0.w,be1.x,be1.y,be1.z,be1.w};
  half8 hv, lv;
#pragma unroll
  for (int j = 0; j < 8; j++) {
    const float xn = (vv[j] - mu) * rsig * gg[j] + bb[j];
    _Float16 hi, lo;
    split_f32(xn, hi, lo);
    hv[j] = hi; lv[j] = lo;
  }
  *(half8*)&xh[(size_t)row * HDIM + tid*8] = hv;
  *(half8*)&xl[(size_t)row * HDIM + tid*8] = lv;
}

// ---------------- GEMM1: C = relu(Xn @ W1c + b1c), X [CHUNK][2048] hi/lo, W1cT [3072][2048] hi/lo
// 128x128 tile, BK=32, 4 waves each 64x64, m97-style global_load_lds staging.
__global__ __launch_bounds__(256, 2) void gemm1_k(
    const _Float16* __restrict__ Ah, const _Float16* __restrict__ Al,
    const _Float16* __restrict__ Bh, const _Float16* __restrict__ Bl,
    const float* __restrict__ bias,
    _Float16* __restrict__ Chi, _Float16* __restrict__ Clo)
{
  __shared__ _Float16 sAh[128*32], sAl[128*32], sBh[128*32], sBl[128*32];
  const int tid = threadIdx.x;
  const int l = tid & 63, w = tid >> 6;
  const int n0 = blockIdx.x * 128, m0 = blockIdx.y * 128;   // x = n-tile (A-panel reuse across consecutive blocks)
  const int wr = (w >> 1) * 64, wc = (w & 1) * 64;

  f32x4 am[4][4] = {}; f32x4 ac[4][4] = {};

  const int s0 = w*128 + l;
  const int r0 = s0 >> 2, c0 = (s0 & 3) << 3;
  const int s1 = s0 + 64;
  const int r1 = s1 >> 2, c1 = (s1 & 3) << 3;
  const int lb0 = (w*128) * 8;        // half index of wave LDS base, instr 0
  const int lb1 = (w*128 + 64) * 8;   // instr 1

  const _Float16* a0h = Ah + (size_t)(m0 + r0) * HDIM + c0;
  const _Float16* a1h = Ah + (size_t)(m0 + r1) * HDIM + c1;
  const _Float16* a0l = Al + (size_t)(m0 + r0) * HDIM + c0;
  const _Float16* a1l = Al + (size_t)(m0 + r1) * HDIM + c1;
  const _Float16* b0h = Bh + (size_t)(n0 + r0) * HDIM + c0;
  const _Float16* b1h = Bh + (size_t)(n0 + r1) * HDIM + c1;
  const _Float16* b0l = Bl + (size_t)(n0 + r0) * HDIM + c0;
  const _Float16* b1l = Bl + (size_t)(n0 + r1) * HDIM + c1;

  const int arow = wr + (l & 15);
  const int brow = wc + (l & 15);
  const int koff = (l >> 4) << 3;

  for (int kt = 0; kt < HDIM; kt += 32) {
    gl_lds16(a0h + kt, &sAh[lb0]);
    gl_lds16(a1h + kt, &sAh[lb1]);
    gl_lds16(a0l + kt, &sAl[lb0]);
    gl_lds16(a1l + kt, &sAl[lb1]);
    gl_lds16(b0h + kt, &sBh[lb0]);
    gl_lds16(b1h + kt, &sBh[lb1]);
    gl_lds16(b0l + kt, &sBl[lb0]);
    gl_lds16(b1l + kt, &sBl[lb1]);
    __syncthreads();                   // compiler drains vmcnt before barrier
    half8 afh[4], afl[4], bfh[4], bfl[4];
#pragma unroll
    for (int m = 0; m < 4; m++) {
      afh[m] = *(const half8*)&sAh[(arow + m*16)*32 + koff];
      afl[m] = *(const half8*)&sAl[(arow + m*16)*32 + koff];
    }
#pragma unroll
    for (int n = 0; n < 4; n++) {
      bfh[n] = *(const half8*)&sBh[(brow + n*16)*32 + koff];
      bfl[n] = *(const half8*)&sBl[(brow + n*16)*32 + koff];
    }
#pragma unroll
    for (int m = 0; m < 4; m++)
#pragma unroll
      for (int n = 0; n < 4; n++) {
        am[m][n] = mfma16(afh[m], bfh[n], am[m][n]);
        ac[m][n] = mfma16(afl[m], bfh[n], ac[m][n]);
        ac[m][n] = mfma16(afh[m], bfl[n], ac[m][n]);
      }
    __syncthreads();
  }
  // epilogue: bias + relu + hi/lo split store
#pragma unroll
  for (int n = 0; n < 4; n++) {
    const int col = n0 + wc + n*16 + (l & 15);
    const float bv = bias[col];
#pragma unroll
    for (int m = 0; m < 4; m++) {
      const int rowb = m0 + wr + m*16 + ((l >> 4) << 2);
#pragma unroll
      for (int r = 0; r < 4; r++) {
        float v = am[m][n][r] + ac[m][n][r] * INV_LO_SCALE + bv;
        v = fmaxf(v, 0.0f);
        _Float16 hh, ll;
        split_f32(v, hh, ll);
        const size_t o = (size_t)(rowb + r) * N1 + col;
        Chi[o] = hh; Clo[o] = ll;
      }
    }
  }
}

// ---------------- GEMM2: partial logits = h @ W2c, K-split x2 into L0/L1. BM=64, N=64.
__global__ __launch_bounds__(256) void gemm2_k(
    const _Float16* __restrict__ Ah, const _Float16* __restrict__ Al,
    const _Float16* __restrict__ Bh, const _Float16* __restrict__ Bl,
    float* __restrict__ L0, float* __restrict__ L1, int gt0)
{
  __shared__ _Float16 sAh[64*32], sAl[64*32], sBh[64*32], sBl[64*32];
  const int tid = threadIdx.x, l = tid & 63, w = tid >> 6;
  const int tile = blockIdx.x >> 1, kh = blockIdx.x & 1;
  const int t0 = tile * 64;
  const int k0 = kh * 1536;
  f32x4 am[4] = {}, ac[4] = {};
  const int s = w*64 + l;
  const int rr = s >> 2, cc = (s & 3) << 3;
  const int lb = (w*64) * 8;
  const _Float16* pah = Ah + (size_t)(t0 + rr) * N1 + cc;
  const _Float16* pal = Al + (size_t)(t0 + rr) * N1 + cc;
  const _Float16* pbh = Bh + (size_t)rr * N1 + cc;
  const _Float16* pbl = Bl + (size_t)rr * N1 + cc;
  const int arow = (w*16 + (l & 15))*32 + ((l >> 4) << 3);
  const int koff = (l >> 4) << 3;
  for (int kt = k0; kt < k0 + 1536; kt += 32) {
    gl_lds16(pah + kt, &sAh[lb]);
    gl_lds16(pal + kt, &sAl[lb]);
    gl_lds16(pbh + kt, &sBh[lb]);
    gl_lds16(pbl + kt, &sBl[lb]);
    __syncthreads();
    const half8 ah  = *(const half8*)&sAh[arow];
    const half8 al8 = *(const half8*)&sAl[arow];
#pragma unroll
    for (int n = 0; n < 4; n++) {
      const half8 bh  = *(const half8*)&sBh[(n*16 + (l & 15))*32 + koff];
      const half8 bl8 = *(const half8*)&sBl[(n*16 + (l & 15))*32 + koff];
      am[n] = mfma16(ah, bh, am[n]);
      ac[n] = mfma16(al8, bh, ac[n]);
      ac[n] = mfma16(ah, bl8, ac[n]);
    }
    __syncthreads();
  }
  float* dst = kh ? L1 : L0;
#pragma unroll
  for (int n = 0; n < 4; n++) {
    const int col = n*16 + (l & 15);
#pragma unroll
    for (int r = 0; r < 4; r++) {
      const int row = w*16 + ((l >> 4) << 2) + r;
      dst[(size_t)(gt0 + t0 + row) * NEXP + col] = am[n][r] + ac[n][r] * INV_LO_SCALE;
    }
  }
}

// ---------------- softmax + top2 + outputs + per-expert prob sums. One wave per token.
__global__ __launch_bounds__(256) void softmax_topk_k(
    const float* __restrict__ L0, const float* __restrict__ L1,
    const float* __restrict__ b2c, float* __restrict__ out, float* __restrict__ gloads)
{
  __shared__ float lred[4][64];
  const int tid = threadIdx.x, l = tid & 63, w = tid >> 6;
  const int tb = blockIdx.x * 16;
  const float bc = b2c[l];
  float psum = 0.0f;
#pragma unroll
  for (int it = 0; it < 4; it++) {
    const int t = tb + w*4 + it;
    const size_t o = (size_t)t * NEXP + l;
    const float c = L0[o] + L1[o] + bc;
    // top-1 (ties -> lower index, matching jax.lax.top_k stability)
    float v1 = c; int i1 = l;
    for (int off = 1; off < 64; off <<= 1) {
      const float ov = __shfl_xor(v1, off);
      const int   oi = __shfl_xor(i1, off);
      if (ov > v1 || (ov == v1 && oi < i1)) { v1 = ov; i1 = oi; }
    }
    const float c2 = (l == i1) ? -3.0e38f : c;
    float v2 = c2; int i2 = l;
    for (int off = 1; off < 64; off <<= 1) {
      const float ov = __shfl_xor(v2, off);
      const int   oi = __shfl_xor(i2, off);
      if (ov > v2 || (ov == v2 && oi < i2)) { v2 = ov; i2 = oi; }
    }
    const float e = expf(c - v1);
    float Z = e;
    for (int off = 1; off < 64; off <<= 1) Z += __shfl_xor(Z, off);
    psum += e / Z;
    if (l == 0) {
      const float e2 = expf(v2 - v1);
      const float inv = 1.0f / (1.0f + e2);
      out[2*t]     = (float)i1;
      out[2*t + 1] = (float)i2;
      out[2*TOKENS + 2*t]     = inv;
      out[2*TOKENS + 2*t + 1] = e2 * inv;
    }
  }
  lred[w][l] = psum;
  __syncthreads();
  if (tid < 64)
    atomicAdd(&gloads[tid], lred[0][tid] + lred[1][tid] + lred[2][tid] + lred[3][tid]);
}

__global__ void finalize_k(const float* __restrict__ gloads, const float* __restrict__ eloads,
                           float* __restrict__ out)
{
  const int e = threadIdx.x;
  const float nl = 0.9f * eloads[e] + 0.1f * (gloads[e] * (1.0f / (float)TOKENS));
  float tot = nl;
  for (int off = 1; off < 64; off <<= 1) tot += __shfl_xor(tot, off);
  const float target = tot * (1.0f / (float)NEXP);
  const float d = nl - target;
  float aux = d * d;
  for (int off = 1; off < 64; off <<= 1) aux += __shfl_xor(aux, off);
  out[4*TOKENS + 1 + e] = nl;            // new_loads at 65537+
  if (e == 0) out[4*TOKENS] = aux;       // aux_loss at 65536
}

extern "C" void kernel_launch(void* const* d_in, const int* in_sizes, int n_in,
                              void* d_out, int out_size, void* d_ws, size_t ws_size,
                              hipStream_t stream)
{
  (void)in_sizes; (void)n_in; (void)out_size; (void)ws_size;
  const float* x      = (const float*)d_in[0];
  const float* gam    = (const float*)d_in[1];
  const float* bet    = (const float*)d_in[2];
  const float* w1     = (const float*)d_in[3];
  const float* b1     = (const float*)d_in[4];
  const float* w2     = (const float*)d_in[5];
  const float* b2     = (const float*)d_in[6];
  const float* lw1    = (const float*)d_in[7];
  const float* lb1    = (const float*)d_in[8];
  const float* lw2    = (const float*)d_in[9];
  const float* lb2    = (const float*)d_in[10];
  const float* eloads = (const float*)d_in[11];
  float* out = (float*)d_out;

  char* ws = (char*)d_ws;
  _Float16* xh   = (_Float16*)(ws + 0);            // 16384x2048 f16        67108864
  _Float16* xl   = (_Float16*)(ws + 67108864);     //                       67108864
  _Float16* w1th = (_Float16*)(ws + 134217728);    // 3072x2048 f16         12582912
  _Float16* w1tl = (_Float16*)(ws + 146800640);    //                       12582912
  _Float16* w2th = (_Float16*)(ws + 159383552);    // 64x3072 f16             393216
  _Float16* w2tl = (_Float16*)(ws + 159776768);    //                         393216
  float*    b1c  = (float*)   (ws + 160169984);    // 3072 f32                 12288
  float*    b2c  = (float*)   (ws + 160182272);    // 64 f32                     256
  _Float16* hh   = (_Float16*)(ws + 160182528);    // 8192x3072 f16         50331648
  _Float16* hl   = (_Float16*)(ws + 210514176);    //                       50331648
  float*    L0   = (float*)   (ws + 260845824);    // 16384x64 f32           4194304
  float*    L1   = (float*)   (ws + 265040128);    //                        4194304
  float*    gld  = (float*)   (ws + 269234432);    // 64 f32                     256

  hipMemsetAsync(gld, 0, 64 * sizeof(float), stream);

  // weight prep: W1cT = [w1 | lw1]^T  (3072 x 2048), W2cT = [w2 ; 0.01*lw2]^T (64 x 3072)
  transpose_split_k<<<dim3(64, 64), 256, 0, stream>>>(w1,  2048, 2048, 2048, w1th, w1tl, 2048, 0,    0,    1.0f);
  transpose_split_k<<<dim3(64, 32), 256, 0, stream>>>(lw1, 2048, 1024, 1024, w1th, w1tl, 2048, 2048, 0,    1.0f);
  transpose_split_k<<<dim3(64, 2),  256, 0, stream>>>(w2,  2048, 64,   64,   w2th, w2tl, 3072, 0,    0,    1.0f);
  transpose_split_k<<<dim3(32, 2),  256, 0, stream>>>(lw2, 1024, 64,   64,   w2th, w2tl, 3072, 0,    2048, 0.01f);
  prep_bias_k<<<13, 256, 0, stream>>>(b1, lb1, b2, lb2, b1c, b2c);

  ln_split_k<<<TOKENS, 256, 0, stream>>>(x, gam, bet, xh, xl);

  for (int c = 0; c < 2; c++) {
    const size_t tok0 = (size_t)c * CHUNK;
    gemm1_k<<<dim3(N1/128, CHUNK/128), 256, 0, stream>>>(
        xh + tok0 * HDIM, xl + tok0 * HDIM, w1th, w1tl, b1c, hh, hl);
    gemm2_k<<<dim3((CHUNK/64) * 2), 256, 0, stream>>>(
        hh, hl, w2th, w2tl, L0, L1, (int)tok0);
  }

  softmax_topk_k<<<TOKENS/16, 256, 0, stream>>>(L0, L1, b2c, out, gld);
  finalize_k<<<1, 64, 0, stream>>>(gld, eloads, out);
}

// Round 2
// 919.128 us; speedup vs baseline: 1.0862x; 1.0862x over previous
//
#include <hip/hip_runtime.h>
#include <hip/hip_bf16.h>
#include <stdint.h>

// EPLB router: LN -> fused [router+balance] MLP -> softmax/top2/EMA.
// Round 2: GEMM1 rebuilt as counted-vmcnt pipeline (3 LDS bufs, depth-2 prefetch,
// vmcnt(12), setprio) with GEMM2 fused into the epilogue (partial logits per n-block).

#define TOKENS 16384
#define HDIM   2048
#define N1     3072
#define NEXP   64
#define NPART  24            // N1/128 n-blocks -> logit partials
#define LO_SCALE 2048.0f
#define INV_LO_SCALE (1.0f/2048.0f)

typedef _Float16 half8 __attribute__((ext_vector_type(8)));
typedef float f32x4 __attribute__((ext_vector_type(4)));

__device__ __forceinline__ void gl_lds16(const void* g, void* l) {
  __builtin_amdgcn_global_load_lds((__attribute__((address_space(1))) void*)(g),
                                   (__attribute__((address_space(3))) void*)(l),
                                   16, 0, 0);
}

__device__ __forceinline__ f32x4 mfma16(half8 a, half8 b, f32x4 c) {
  return __builtin_amdgcn_mfma_f32_16x16x32_f16(a, b, c, 0, 0, 0);
}

__device__ __forceinline__ void split_f32(float v, _Float16& hi, _Float16& lo) {
  hi = (_Float16)v;
  lo = (_Float16)((v - (float)hi) * LO_SCALE);
}

// ---------------- weight transpose + split
__global__ __launch_bounds__(256) void transpose_split_k(
    const float* __restrict__ src, int R, int C, int src_ld,
    _Float16* __restrict__ dst_hi, _Float16* __restrict__ dst_lo,
    int dst_ld, int row_off, int col_off, float scale)
{
  __shared__ float tile[32][33];
  const int tx = threadIdx.x & 31, ty = threadIdx.x >> 5;
  const int r0 = blockIdx.x * 32, c0 = blockIdx.y * 32;
#pragma unroll
  for (int i = 0; i < 4; i++)
    tile[ty + i*8][tx] = src[(size_t)(r0 + ty + i*8) * src_ld + c0 + tx];
  __syncthreads();
#pragma unroll
  for (int i = 0; i < 4; i++) {
    const int c = c0 + ty + i*8;
    const int r = r0 + tx;
    const float v = tile[tx][ty + i*8] * scale;
    _Float16 h, l;
    split_f32(v, h, l);
    const size_t o = (size_t)(c + row_off) * dst_ld + (r + col_off);
    dst_hi[o] = h; dst_lo[o] = l;
  }
}

__global__ void prep_bias_k(const float* __restrict__ b1, const float* __restrict__ lb1,
                            const float* __restrict__ b2, const float* __restrict__ lb2,
                            float* __restrict__ b1c, float* __restrict__ b2c)
{
  const int i = blockIdx.x * 256 + threadIdx.x;
  if (i < 2048)      b1c[i] = b1[i];
  else if (i < 3072) b1c[i] = lb1[i - 2048];
  else if (i < 3136) { const int e = i - 3072; b2c[e] = b2[e] + 0.01f * lb2[e]; }
}

// ---------------- LayerNorm + f16 hi/lo split store
__global__ __launch_bounds__(256) void ln_split_k(
    const float* __restrict__ x, const float* __restrict__ gamma, const float* __restrict__ beta,
    _Float16* __restrict__ xh, _Float16* __restrict__ xl)
{
  const int row = blockIdx.x, tid = threadIdx.x, l = tid & 63, w = tid >> 6;
  const float* xr = x + (size_t)row * HDIM;
  const float4 v0 = ((const float4*)xr)[tid*2];
  const float4 v1 = ((const float4*)xr)[tid*2 + 1];
  float vv[8] = {v0.x, v0.y, v0.z, v0.w, v1.x, v1.y, v1.z, v1.w};
  float s = 0.0f;
#pragma unroll
  for (int j = 0; j < 8; j++) s += vv[j];
  for (int off = 1; off < 64; off <<= 1) s += __shfl_xor(s, off);
  __shared__ float r1[4], r2[4];
  if (l == 0) r1[w] = s;
  __syncthreads();
  const float mu = (r1[0] + r1[1] + r1[2] + r1[3]) * (1.0f / HDIM);
  float q = 0.0f;
#pragma unroll
  for (int j = 0; j < 8; j++) { const float d = vv[j] - mu; q += d * d; }
  for (int off = 1; off < 64; off <<= 1) q += __shfl_xor(q, off);
  if (l == 0) r2[w] = q;
  __syncthreads();
  const float var = (r2[0] + r2[1] + r2[2] + r2[3]) * (1.0f / HDIM);
  const float rsig = 1.0f / sqrtf(var + 1e-5f);
  const float4 g0 = ((const float4*)gamma)[tid*2];
  const float4 g1 = ((const float4*)gamma)[tid*2 + 1];
  const float4 be0 = ((const float4*)beta)[tid*2];
  const float4 be1 = ((const float4*)beta)[tid*2 + 1];
  const float gg[8] = {g0.x,g0.y,g0.z,g0.w,g1.x,g1.y,g1.z,g1.w};
  const float bb[8] = {be0.x,be0.y,be0.z,be0.w,be1.x,be1.y,be1.z,be1.w};
  half8 hv, lv;
#pragma unroll
  for (int j = 0; j < 8; j++) {
    const float xn = (vv[j] - mu) * rsig * gg[j] + bb[j];
    _Float16 hi, lo;
    split_f32(xn, hi, lo);
    hv[j] = hi; lv[j] = lo;
  }
  *(half8*)&xh[(size_t)row * HDIM + tid*8] = hv;
  *(half8*)&xl[(size_t)row * HDIM + tid*8] = lv;
}

// ---------------- GEMM1 fused: 256x128 tile, BK=32, 8 waves (32 rows x 128 cols each),
// 3-buffer depth-2 prefetch with counted vmcnt; epilogue = relu+split + fused GEMM2
// against W2 slice -> partial logits Lp[nblk][token][64].
// LDS layout per buf (49152 B): A: 256 rows x 128 B (hi|lo interleaved, slot-swizzled),
// B at +32768: 128 rows x 128 B. Swizzle: phys_slot = logical_slot ^ (row&7).
#define BUFB 49152

__global__ __launch_bounds__(512, 2) void gemm1_fused_k(
    const _Float16* __restrict__ xh, const _Float16* __restrict__ xl,
    const _Float16* __restrict__ w1th, const _Float16* __restrict__ w1tl,
    const _Float16* __restrict__ w2th, const _Float16* __restrict__ w2tl,
    const float* __restrict__ b1c, float* __restrict__ Lp)
{
  extern __shared__ char smem[];
  const int tid = threadIdx.x;
  const int i = tid & 63, w = tid >> 6;
  const int bid = blockIdx.x;
  const int swz = (bid & 7) * 192 + (bid >> 3);     // 1536 = 8*192, bijective
  const int nblk = swz % 24, mblk = swz / 24;
  const int m0 = mblk * 256, n0 = nblk * 128;

  // --- staging sources: pre-swizzled global addresses, linear LDS dests
  const _Float16* srcA[4]; int ldsA[4];
  const _Float16* srcB[2]; int ldsB[2];
#pragma unroll
  for (int j = 0; j < 4; j++) {
    const int r = (w*4 + j)*8 + (i >> 3);
    const int s = (i & 7) ^ (r & 7);                 // logical slot for my phys slot
    srcA[j] = (s < 4 ? xh : xl) + (size_t)(m0 + r) * HDIM + (s & 3) * 8;
    ldsA[j] = (w*4 + j) * 1024;
  }
#pragma unroll
  for (int j = 0; j < 2; j++) {
    const int r = (w*2 + j)*8 + (i >> 3);
    const int s = (i & 7) ^ (r & 7);
    srcB[j] = (s < 4 ? w1th : w1tl) + (size_t)(n0 + r) * HDIM + (s & 3) * 8;
    ldsB[j] = 32768 + (w*2 + j) * 1024;
  }

  // --- fragment read offsets (row&7 == i&7 for all frag rows)
  const int aoff = (w*32 + (i & 15))*128 + (((i >> 4) ^ (i & 7)) << 4);
  const int boff = 32768 + (i & 15)*128 + (((i >> 4) ^ (i & 7)) << 4);

  f32x4 am[2][8] = {{{0}}};
  f32x4 ac[2][8] = {{{0}}};

#define STAGE(BUF, KT) { \
    char* _b = smem + (BUF)*BUFB; \
    gl_lds16(srcA[0] + (KT), _b + ldsA[0]); \
    gl_lds16(srcA[1] + (KT), _b + ldsA[1]); \
    gl_lds16(srcA[2] + (KT), _b + ldsA[2]); \
    gl_lds16(srcA[3] + (KT), _b + ldsA[3]); \
    gl_lds16(srcB[0] + (KT), _b + ldsB[0]); \
    gl_lds16(srcB[1] + (KT), _b + ldsB[1]); }

#define BODY(BUF, VM) { \
    asm volatile("s_waitcnt vmcnt(" #VM ")" ::: "memory"); \
    __builtin_amdgcn_s_barrier(); \
    const char* bp = smem + (BUF)*BUFB; \
    half8 afh[2], afl[2], bfh[8], bfl[8]; \
    _Pragma("unroll") for (int m = 0; m < 2; m++) { \
      afh[m] = *(const half8*)(bp + aoff + m*2048); \
      afl[m] = *(const half8*)(bp + (aoff ^ 64) + m*2048); } \
    _Pragma("unroll") for (int n = 0; n < 8; n++) { \
      bfh[n] = *(const half8*)(bp + boff + n*2048); \
      bfl[n] = *(const half8*)(bp + (boff ^ 64) + n*2048); } \
    __builtin_amdgcn_s_setprio(1); \
    _Pragma("unroll") for (int m = 0; m < 2; m++) \
      _Pragma("unroll") for (int n = 0; n < 8; n++) \
        am[m][n] = mfma16(afh[m], bfh[n], am[m][n]); \
    _Pragma("unroll") for (int m = 0; m < 2; m++) \
      _Pragma("unroll") for (int n = 0; n < 8; n++) \
        ac[m][n] = mfma16(afl[m], bfh[n], ac[m][n]); \
    _Pragma("unroll") for (int m = 0; m < 2; m++) \
      _Pragma("unroll") for (int n = 0; n < 8; n++) \
        ac[m][n] = mfma16(afh[m], bfl[n], ac[m][n]); \
    __builtin_amdgcn_s_setprio(0); \
    __builtin_amdgcn_s_barrier(); }

  STAGE(0, 0)
  STAGE(1, 32)
  int buf = 0;
  for (int t = 0; t < 62; t++) {
    int b2 = buf + 2; if (b2 >= 3) b2 -= 3;
    STAGE(b2, (t + 2) * 32)
    BODY(buf, 12)
    buf = (buf + 1 == 3) ? 0 : buf + 1;
  }
  BODY(buf, 6)
  buf = (buf + 1 == 3) ? 0 : buf + 1;
  BODY(buf, 0)
#undef STAGE
#undef BODY

  // ---- epilogue: h = relu(am + ac/2048 + b1), split, LDS transpose (packed u32)
  float bv[8];
#pragma unroll
  for (int n = 0; n < 8; n++) bv[n] = b1c[n0 + n*16 + (i & 15)];

  char* hw = smem + w * 16384;   // 32 rows x 128 cells x 4B, swizzled
#pragma unroll
  for (int m = 0; m < 2; m++)
#pragma unroll
    for (int n = 0; n < 8; n++)
#pragma unroll
      for (int r = 0; r < 4; r++) {
        const int lr = m*16 + (i >> 4)*4 + r;
        const int lc = n*16 + (i & 15);
        float v = am[m][n][r] + ac[m][n][r] * INV_LO_SCALE + bv[n];
        v = fmaxf(v, 0.0f);
        _Float16 hh, ll;
        split_f32(v, hh, ll);
        const uint32_t pk = (uint32_t)__builtin_bit_cast(unsigned short, hh) |
                            ((uint32_t)__builtin_bit_cast(unsigned short, ll) << 16);
        const int pc = lc ^ ((lr & 3) << 2) ^ (((lr >> 2) & 3) << 4);
        *(uint32_t*)(hw + lr*512 + pc*4) = pk;
      }
  asm volatile("s_waitcnt lgkmcnt(0)" ::: "memory");
  __builtin_amdgcn_sched_barrier(0);

  // ---- fused GEMM2: logits_partial = h(32x128) @ W2c[n0:n0+128, 0:64]
  f32x4 la[2][4] = {{{0}}};
  f32x4 lc2[2][4] = {{{0}}};
#pragma unroll
  for (int ks = 0; ks < 4; ks++) {
    half8 wh[4], wl[4];
#pragma unroll
    for (int e = 0; e < 4; e++) {
      const size_t wo = (size_t)(e*16 + (i & 15)) * N1 + n0 + ks*32 + ((i >> 4) << 3);
      wh[e] = *(const half8*)(w2th + wo);
      wl[e] = *(const half8*)(w2tl + wo);
    }
#pragma unroll
    for (int m2 = 0; m2 < 2; m2++) {
      const int lr = m2*16 + (i & 15);
      const int c0 = ks*32 + ((i >> 4) << 3);
      const int x1 = ((lr & 3) << 2) ^ (((lr >> 2) & 3) << 4);
      const uint4 cl0 = *(const uint4*)(hw + lr*512 + ((c0 ^ x1) << 2));
      const uint4 cl1 = *(const uint4*)(hw + lr*512 + (((c0 + 4) ^ x1) << 2));
      const uint32_t cu[8] = {cl0.x, cl0.y, cl0.z, cl0.w, cl1.x, cl1.y, cl1.z, cl1.w};
      half8 pah, pal;
#pragma unroll
      for (int j = 0; j < 8; j++) {
        pah[j] = __builtin_bit_cast(_Float16, (unsigned short)(cu[j] & 0xffff));
        pal[j] = __builtin_bit_cast(_Float16, (unsigned short)(cu[j] >> 16));
      }
#pragma unroll
      for (int e = 0; e < 4; e++) {
        la[m2][e]  = mfma16(pah, wh[e], la[m2][e]);
        lc2[m2][e] = mfma16(pal, wh[e], lc2[m2][e]);
        lc2[m2][e] = mfma16(pah, wl[e], lc2[m2][e]);
      }
    }
  }

  float* lpb = Lp + ((size_t)nblk * TOKENS + m0 + w*32) * NEXP;
#pragma unroll
  for (int m2 = 0; m2 < 2; m2++)
#pragma unroll
    for (int e = 0; e < 4; e++)
#pragma unroll
      for (int r = 0; r < 4; r++) {
        const int row = m2*16 + (i >> 4)*4 + r;
        const int col = e*16 + (i & 15);
        lpb[row*NEXP + col] = la[m2][e][r] + lc2[m2][e][r] * INV_LO_SCALE;
      }
}

// ---------------- softmax + top2 + outputs + per-expert prob sums. One wave per token.
__global__ __launch_bounds__(256) void softmax_topk_k(
    const float* __restrict__ Lp, const float* __restrict__ b2c,
    float* __restrict__ out, float* __restrict__ gloads)
{
  __shared__ float lred[4][64];
  const int tid = threadIdx.x, l = tid & 63, w = tid >> 6;
  const int tb = blockIdx.x * 16;
  const float bc = b2c[l];
  float psum = 0.0f;
#pragma unroll
  for (int it = 0; it < 4; it++) {
    const int t = tb + w*4 + it;
    const float* lp = Lp + (size_t)t * NEXP + l;
    float c = bc;
#pragma unroll
    for (int p = 0; p < NPART; p++) c += lp[(size_t)p * TOKENS * NEXP];
    float v1 = c; int i1 = l;
    for (int off = 1; off < 64; off <<= 1) {
      const float ov = __shfl_xor(v1, off);
      const int   oi = __shfl_xor(i1, off);
      if (ov > v1 || (ov == v1 && oi < i1)) { v1 = ov; i1 = oi; }
    }
    const float c2 = (l == i1) ? -3.0e38f : c;
    float v2 = c2; int i2 = l;
    for (int off = 1; off < 64; off <<= 1) {
      const float ov = __shfl_xor(v2, off);
      const int   oi = __shfl_xor(i2, off);
      if (ov > v2 || (ov == v2 && oi < i2)) { v2 = ov; i2 = oi; }
    }
    const float e = expf(c - v1);
    float Z = e;
    for (int off = 1; off < 64; off <<= 1) Z += __shfl_xor(Z, off);
    psum += e / Z;
    if (l == 0) {
      const float e2 = expf(v2 - v1);
      const float inv = 1.0f / (1.0f + e2);
      out[2*t]     = (float)i1;
      out[2*t + 1] = (float)i2;
      out[2*TOKENS + 2*t]     = inv;
      out[2*TOKENS + 2*t + 1] = e2 * inv;
    }
  }
  lred[w][l] = psum;
  __syncthreads();
  if (tid < 64)
    atomicAdd(&gloads[tid], lred[0][tid] + lred[1][tid] + lred[2][tid] + lred[3][tid]);
}

__global__ void finalize_k(const float* __restrict__ gloads, const float* __restrict__ eloads,
                           float* __restrict__ out)
{
  const int e = threadIdx.x;
  const float nl = 0.9f * eloads[e] + 0.1f * (gloads[e] * (1.0f / (float)TOKENS));
  float tot = nl;
  for (int off = 1; off < 64; off <<= 1) tot += __shfl_xor(tot, off);
  const float target = tot * (1.0f / (float)NEXP);
  const float d = nl - target;
  float aux = d * d;
  for (int off = 1; off < 64; off <<= 1) aux += __shfl_xor(aux, off);
  out[4*TOKENS + 1 + e] = nl;
  if (e == 0) out[4*TOKENS] = aux;
}

extern "C" void kernel_launch(void* const* d_in, const int* in_sizes, int n_in,
                              void* d_out, int out_size, void* d_ws, size_t ws_size,
                              hipStream_t stream)
{
  (void)in_sizes; (void)n_in; (void)out_size; (void)ws_size;
  const float* x      = (const float*)d_in[0];
  const float* gam    = (const float*)d_in[1];
  const float* bet    = (const float*)d_in[2];
  const float* w1     = (const float*)d_in[3];
  const float* b1     = (const float*)d_in[4];
  const float* w2     = (const float*)d_in[5];
  const float* b2     = (const float*)d_in[6];
  const float* lw1    = (const float*)d_in[7];
  const float* lb1    = (const float*)d_in[8];
  const float* lw2    = (const float*)d_in[9];
  const float* lb2    = (const float*)d_in[10];
  const float* eloads = (const float*)d_in[11];
  float* out = (float*)d_out;

  char* ws = (char*)d_ws;
  _Float16* xh   = (_Float16*)(ws + 0);            // 16384x2048 f16      67108864
  _Float16* xl   = (_Float16*)(ws + 67108864);     //                     67108864
  _Float16* w1th = (_Float16*)(ws + 134217728);    // 3072x2048 f16       12582912
  _Float16* w1tl = (_Float16*)(ws + 146800640);    //                     12582912
  _Float16* w2th = (_Float16*)(ws + 159383552);    // 64x3072 f16           393216
  _Float16* w2tl = (_Float16*)(ws + 159776768);    //                       393216
  float*    b1c  = (float*)   (ws + 160169984);    // 3072 f32               12288
  float*    b2c  = (float*)   (ws + 160182272);    // 64 f32                   256
  float*    Lp   = (float*)   (ws + 160182528);    // 24x16384x64 f32    100663296
  float*    gld  = (float*)   (ws + 260845824);    // 64 f32                   256

  hipMemsetAsync(gld, 0, 64 * sizeof(float), stream);

  transpose_split_k<<<dim3(64, 64), 256, 0, stream>>>(w1,  2048, 2048, 2048, w1th, w1tl, 2048, 0,    0,    1.0f);
  transpose_split_k<<<dim3(64, 32), 256, 0, stream>>>(lw1, 2048, 1024, 1024, w1th, w1tl, 2048, 2048, 0,    1.0f);
  transpose_split_k<<<dim3(64, 2),  256, 0, stream>>>(w2,  2048, 64,   64,   w2th, w2tl, 3072, 0,    0,    1.0f);
  transpose_split_k<<<dim3(32, 2),  256, 0, stream>>>(lw2, 1024, 64,   64,   w2th, w2tl, 3072, 0,    2048, 0.01f);
  prep_bias_k<<<13, 256, 0, stream>>>(b1, lb1, b2, lb2, b1c, b2c);

  ln_split_k<<<TOKENS, 256, 0, stream>>>(x, gam, bet, xh, xl);

  hipFuncSetAttribute((const void*)gemm1_fused_k,
                      hipFuncAttributeMaxDynamicSharedMemorySize, 3 * BUFB);
  gemm1_fused_k<<<1536, 512, 3 * BUFB, stream>>>(xh, xl, w1th, w1tl, w2th, w2tl, b1c, Lp);

  softmax_topk_k<<<TOKENS/16, 256, 0, stream>>>(Lp, b2c, out, gld);
  finalize_k<<<1, 64, 0, stream>>>(gld, eloads, out);
}

// Round 3
// 842.430 us; speedup vs baseline: 1.1851x; 1.0910x over previous
//
#include <hip/hip_runtime.h>
#include <hip/hip_bf16.h>
#include <stdint.h>

// EPLB router: LN -> fused [router+balance] MLP -> softmax/top2/EMA.
// Round 3: GEMM1 K-loop rebuilt as m201-style phased schedule (4 phases/K-tile,
// 12 MFMA each, reads+stage pre-barrier, setprio, counted vmcnt(6) once/tile),
// n-major XCD swizzle for weight-panel L2 residency.

#define TOKENS 16384
#define HDIM   2048
#define N1     3072
#define NEXP   64
#define NPART  24            // N1/128 n-blocks -> logit partials
#define LO_SCALE 2048.0f
#define INV_LO_SCALE (1.0f/2048.0f)

typedef _Float16 half8 __attribute__((ext_vector_type(8)));
typedef float f32x4 __attribute__((ext_vector_type(4)));

__device__ __forceinline__ void gl_lds16(const void* g, void* l) {
  __builtin_amdgcn_global_load_lds((__attribute__((address_space(1))) void*)(g),
                                   (__attribute__((address_space(3))) void*)(l),
                                   16, 0, 0);
}

__device__ __forceinline__ f32x4 mfma16(half8 a, half8 b, f32x4 c) {
  return __builtin_amdgcn_mfma_f32_16x16x32_f16(a, b, c, 0, 0, 0);
}

__device__ __forceinline__ void split_f32(float v, _Float16& hi, _Float16& lo) {
  hi = (_Float16)v;
  lo = (_Float16)((v - (float)hi) * LO_SCALE);
}

// ---------------- weight transpose + split
__global__ __launch_bounds__(256) void transpose_split_k(
    const float* __restrict__ src, int R, int C, int src_ld,
    _Float16* __restrict__ dst_hi, _Float16* __restrict__ dst_lo,
    int dst_ld, int row_off, int col_off, float scale)
{
  __shared__ float tile[32][33];
  const int tx = threadIdx.x & 31, ty = threadIdx.x >> 5;
  const int r0 = blockIdx.x * 32, c0 = blockIdx.y * 32;
#pragma unroll
  for (int i = 0; i < 4; i++)
    tile[ty + i*8][tx] = src[(size_t)(r0 + ty + i*8) * src_ld + c0 + tx];
  __syncthreads();
#pragma unroll
  for (int i = 0; i < 4; i++) {
    const int c = c0 + ty + i*8;
    const int r = r0 + tx;
    const float v = tile[tx][ty + i*8] * scale;
    _Float16 h, l;
    split_f32(v, h, l);
    const size_t o = (size_t)(c + row_off) * dst_ld + (r + col_off);
    dst_hi[o] = h; dst_lo[o] = l;
  }
}

__global__ void prep_bias_k(const float* __restrict__ b1, const float* __restrict__ lb1,
                            const float* __restrict__ b2, const float* __restrict__ lb2,
                            float* __restrict__ b1c, float* __restrict__ b2c)
{
  const int i = blockIdx.x * 256 + threadIdx.x;
  if (i < 2048)      b1c[i] = b1[i];
  else if (i < 3072) b1c[i] = lb1[i - 2048];
  else if (i < 3136) { const int e = i - 3072; b2c[e] = b2[e] + 0.01f * lb2[e]; }
}

// ---------------- LayerNorm + f16 hi/lo split store
__global__ __launch_bounds__(256) void ln_split_k(
    const float* __restrict__ x, const float* __restrict__ gamma, const float* __restrict__ beta,
    _Float16* __restrict__ xh, _Float16* __restrict__ xl)
{
  const int row = blockIdx.x, tid = threadIdx.x, l = tid & 63, w = tid >> 6;
  const float* xr = x + (size_t)row * HDIM;
  const float4 v0 = ((const float4*)xr)[tid*2];
  const float4 v1 = ((const float4*)xr)[tid*2 + 1];
  float vv[8] = {v0.x, v0.y, v0.z, v0.w, v1.x, v1.y, v1.z, v1.w};
  float s = 0.0f;
#pragma unroll
  for (int j = 0; j < 8; j++) s += vv[j];
  for (int off = 1; off < 64; off <<= 1) s += __shfl_xor(s, off);
  __shared__ float r1[4], r2[4];
  if (l == 0) r1[w] = s;
  __syncthreads();
  const float mu = (r1[0] + r1[1] + r1[2] + r1[3]) * (1.0f / HDIM);
  float q = 0.0f;
#pragma unroll
  for (int j = 0; j < 8; j++) { const float d = vv[j] - mu; q += d * d; }
  for (int off = 1; off < 64; off <<= 1) q += __shfl_xor(q, off);
  if (l == 0) r2[w] = q;
  __syncthreads();
  const float var = (r2[0] + r2[1] + r2[2] + r2[3]) * (1.0f / HDIM);
  const float rsig = 1.0f / sqrtf(var + 1e-5f);
  const float4 g0 = ((const float4*)gamma)[tid*2];
  const float4 g1 = ((const float4*)gamma)[tid*2 + 1];
  const float4 be0 = ((const float4*)beta)[tid*2];
  const float4 be1 = ((const float4*)beta)[tid*2 + 1];
  const float gg[8] = {g0.x,g0.y,g0.z,g0.w,g1.x,g1.y,g1.z,g1.w};
  const float bb[8] = {be0.x,be0.y,be0.z,be0.w,be1.x,be1.y,be1.z,be1.w};
  half8 hv, lv;
#pragma unroll
  for (int j = 0; j < 8; j++) {
    const float xn = (vv[j] - mu) * rsig * gg[j] + bb[j];
    _Float16 hi, lo;
    split_f32(xn, hi, lo);
    hv[j] = hi; lv[j] = lo;
  }
  *(half8*)&xh[(size_t)row * HDIM + tid*8] = hv;
  *(half8*)&xl[(size_t)row * HDIM + tid*8] = lv;
}

// ---------------- GEMM1 fused, phased schedule.
// 256x128 tile, BK=32, 8 waves each 32 rows x 128 cols. 3 LDS bufs (48KB each).
// Per K-tile: 4 phases (n-quarters), each {reads; 2 gl_lds; s_barrier; 12 MFMA}.
// vmcnt(6) at q3 only. Epilogue = relu+split + fused GEMM2 -> partial logits.
#define BUFB 49152

__global__ __launch_bounds__(512, 2) void gemm1_fused_k(
    const _Float16* __restrict__ xh, const _Float16* __restrict__ xl,
    const _Float16* __restrict__ w1th, const _Float16* __restrict__ w1tl,
    const _Float16* __restrict__ w2th, const _Float16* __restrict__ w2tl,
    const float* __restrict__ b1c, float* __restrict__ Lp)
{
  extern __shared__ char smem[];
  const int tid = threadIdx.x;
  const int i = tid & 63, w = tid >> 6;
  const int bid = blockIdx.x;
  // n-major XCD swizzle: XCD x owns nblk {3x..3x+2} (3MB W1 slice, L2-resident), iterates m.
  const int xcd = bid & 7, loc = bid >> 3;          // loc 0..191
  const int nblk = xcd * 3 + (loc % 3), mblk = loc / 3;
  const int m0 = mblk * 256, n0 = nblk * 128;

  // --- staging sources: pre-swizzled global addresses, linear LDS dests
  const _Float16* srcA[4]; int ldsA[4];
  const _Float16* srcB[2]; int ldsB[2];
#pragma unroll
  for (int j = 0; j < 4; j++) {
    const int r = (w*4 + j)*8 + (i >> 3);
    const int s = (i & 7) ^ (r & 7);                 // logical slot for my phys slot
    srcA[j] = (s < 4 ? xh : xl) + (size_t)(m0 + r) * HDIM + (s & 3) * 8;
    ldsA[j] = (w*4 + j) * 1024;
  }
#pragma unroll
  for (int j = 0; j < 2; j++) {
    const int r = (w*2 + j)*8 + (i >> 3);
    const int s = (i & 7) ^ (r & 7);
    srcB[j] = (s < 4 ? w1th : w1tl) + (size_t)(n0 + r) * HDIM + (s & 3) * 8;
    ldsB[j] = 32768 + (w*2 + j) * 1024;
  }

  // --- fragment read offsets (row&7 == i&7 for all frag rows)
  const int aoff = (w*32 + (i & 15))*128 + (((i >> 4) ^ (i & 7)) << 4);
  const int boff = 32768 + (i & 15)*128 + (((i >> 4) ^ (i & 7)) << 4);

  f32x4 am[2][8] = {{{0}}};
  f32x4 ac[2][8] = {{{0}}};

#define STG_A01(BUF, KT) { char* _b = smem + (BUF)*BUFB; \
    gl_lds16(srcA[0] + (KT), _b + ldsA[0]); \
    gl_lds16(srcA[1] + (KT), _b + ldsA[1]); }
#define STG_A23(BUF, KT) { char* _b = smem + (BUF)*BUFB; \
    gl_lds16(srcA[2] + (KT), _b + ldsA[2]); \
    gl_lds16(srcA[3] + (KT), _b + ldsA[3]); }
#define STG_B(BUF, KT) { char* _b = smem + (BUF)*BUFB; \
    gl_lds16(srcB[0] + (KT), _b + ldsB[0]); \
    gl_lds16(srcB[1] + (KT), _b + ldsB[1]); }

#define LDF(off) (*(const half8*)(bp + (off)))

#define MMQ(N, BH, BL) { \
    am[0][N] = mfma16(afh0, BH, am[0][N]); \
    ac[0][N] = mfma16(afl0, BH, ac[0][N]); \
    ac[0][N] = mfma16(afh0, BL, ac[0][N]); \
    am[1][N] = mfma16(afh1, BH, am[1][N]); \
    ac[1][N] = mfma16(afl1, BH, ac[1][N]); \
    ac[1][N] = mfma16(afh1, BL, ac[1][N]); }

// One K-tile = 4 phases. Reads + stage issued pre-barrier; MFMA post-barrier.
#define TILE(BUF, SBUF, SKT, DOSTAGE, VMS) { \
    const char* bp = smem + (BUF)*BUFB; \
    half8 afh0, afl0, afh1, afl1, bh0, bl0, bh1, bl1; \
    /* q0: A frags + B n0,n1 */ \
    afh0 = LDF(aoff);            afl0 = LDF(aoff ^ 64); \
    afh1 = LDF(aoff + 2048);     afl1 = LDF((aoff + 2048) ^ 64); \
    bh0  = LDF(boff);            bl0  = LDF(boff ^ 64); \
    bh1  = LDF(boff + 2048);     bl1  = LDF((boff + 2048) ^ 64); \
    if (DOSTAGE) STG_A01(SBUF, SKT); \
    __builtin_amdgcn_sched_barrier(0); \
    __builtin_amdgcn_s_barrier(); \
    __builtin_amdgcn_s_setprio(1); \
    MMQ(0, bh0, bl0) \
    MMQ(1, bh1, bl1) \
    __builtin_amdgcn_s_setprio(0); \
    __builtin_amdgcn_sched_barrier(0); \
    /* q1: B n2,n3 */ \
    bh0 = LDF(boff + 4096);      bl0 = LDF((boff + 4096) ^ 64); \
    bh1 = LDF(boff + 6144);      bl1 = LDF((boff + 6144) ^ 64); \
    if (DOSTAGE) STG_A23(SBUF, SKT); \
    __builtin_amdgcn_sched_barrier(0); \
    __builtin_amdgcn_s_barrier(); \
    __builtin_amdgcn_s_setprio(1); \
    MMQ(2, bh0, bl0) \
    MMQ(3, bh1, bl1) \
    __builtin_amdgcn_s_setprio(0); \
    __builtin_amdgcn_sched_barrier(0); \
    /* q2: B n4,n5 */ \
    bh0 = LDF(boff + 8192);      bl0 = LDF((boff + 8192) ^ 64); \
    bh1 = LDF(boff + 10240);     bl1 = LDF((boff + 10240) ^ 64); \
    if (DOSTAGE) STG_B(SBUF, SKT); \
    __builtin_amdgcn_sched_barrier(0); \
    __builtin_amdgcn_s_barrier(); \
    __builtin_amdgcn_s_setprio(1); \
    MMQ(4, bh0, bl0) \
    MMQ(5, bh1, bl1) \
    __builtin_amdgcn_s_setprio(0); \
    __builtin_amdgcn_sched_barrier(0); \
    /* q3: B n6,n7 + counted vmcnt */ \
    bh0 = LDF(boff + 12288);     bl0 = LDF((boff + 12288) ^ 64); \
    bh1 = LDF(boff + 14336);     bl1 = LDF((boff + 14336) ^ 64); \
    __builtin_amdgcn_sched_barrier(0); \
    asm volatile("s_waitcnt vmcnt(" VMS ")" ::: "memory"); \
    __builtin_amdgcn_s_barrier(); \
    __builtin_amdgcn_s_setprio(1); \
    MMQ(6, bh0, bl0) \
    MMQ(7, bh1, bl1) \
    __builtin_amdgcn_s_setprio(0); \
    __builtin_amdgcn_sched_barrier(0); }

  // prologue: stage tiles 0 and 1
  STG_A01(0, 0)  STG_A23(0, 0)  STG_B(0, 0)
  STG_A01(1, 32) STG_A23(1, 32) STG_B(1, 32)
  asm volatile("s_waitcnt vmcnt(6)" ::: "memory");
  __builtin_amdgcn_s_barrier();

  // main loop: t = 3u,3u+1,3u+2 for u<20 (t=0..59), staging t+2
  for (int u = 0; u < 20; u++) {
    const int kt = (3*u + 2) * 32;
    TILE(0, 2, kt,        1, "6")
    TILE(1, 0, kt + 32,   1, "6")
    TILE(2, 1, kt + 64,   1, "6")
  }
  TILE(0, 2, 62*32, 1, "6")   // t=60 stages 62
  TILE(1, 0, 63*32, 1, "6")   // t=61 stages 63
  TILE(2, 0, 0,     0, "0")   // t=62
  TILE(0, 0, 0,     0, "0")   // t=63
#undef TILE
#undef MMQ
#undef LDF
#undef STG_A01
#undef STG_A23
#undef STG_B

  __builtin_amdgcn_s_barrier();   // all K-loop LDS reads done before epilogue overwrites

  // ---- epilogue: h = relu(am + ac/2048 + b1), split, LDS transpose (packed u32)
  float bv[8];
#pragma unroll
  for (int n = 0; n < 8; n++) bv[n] = b1c[n0 + n*16 + (i & 15)];

  char* hw = smem + w * 16384;   // 32 rows x 128 cells x 4B, swizzled
#pragma unroll
  for (int m = 0; m < 2; m++)
#pragma unroll
    for (int n = 0; n < 8; n++)
#pragma unroll
      for (int r = 0; r < 4; r++) {
        const int lr = m*16 + (i >> 4)*4 + r;
        const int lc = n*16 + (i & 15);
        float v = am[m][n][r] + ac[m][n][r] * INV_LO_SCALE + bv[n];
        v = fmaxf(v, 0.0f);
        _Float16 hh, ll;
        split_f32(v, hh, ll);
        const uint32_t pk = (uint32_t)__builtin_bit_cast(unsigned short, hh) |
                            ((uint32_t)__builtin_bit_cast(unsigned short, ll) << 16);
        const int pc = lc ^ ((lr & 3) << 2) ^ (((lr >> 2) & 3) << 4);
        *(uint32_t*)(hw + lr*512 + pc*4) = pk;
      }
  asm volatile("s_waitcnt lgkmcnt(0)" ::: "memory");
  __builtin_amdgcn_sched_barrier(0);

  // ---- fused GEMM2: logits_partial = h(32x128) @ W2c[n0:n0+128, 0:64]
  f32x4 la[2][4] = {{{0}}};
  f32x4 lc2[2][4] = {{{0}}};
#pragma unroll
  for (int ks = 0; ks < 4; ks++) {
    half8 wh[4], wl[4];
#pragma unroll
    for (int e = 0; e < 4; e++) {
      const size_t wo = (size_t)(e*16 + (i & 15)) * N1 + n0 + ks*32 + ((i >> 4) << 3);
      wh[e] = *(const half8*)(w2th + wo);
      wl[e] = *(const half8*)(w2tl + wo);
    }
#pragma unroll
    for (int m2 = 0; m2 < 2; m2++) {
      const int lr = m2*16 + (i & 15);
      const int c0 = ks*32 + ((i >> 4) << 3);
      const int x1 = ((lr & 3) << 2) ^ (((lr >> 2) & 3) << 4);
      const uint4 cl0 = *(const uint4*)(hw + lr*512 + ((c0 ^ x1) << 2));
      const uint4 cl1 = *(const uint4*)(hw + lr*512 + (((c0 + 4) ^ x1) << 2));
      const uint32_t cu[8] = {cl0.x, cl0.y, cl0.z, cl0.w, cl1.x, cl1.y, cl1.z, cl1.w};
      half8 pah, pal;
#pragma unroll
      for (int j = 0; j < 8; j++) {
        pah[j] = __builtin_bit_cast(_Float16, (unsigned short)(cu[j] & 0xffff));
        pal[j] = __builtin_bit_cast(_Float16, (unsigned short)(cu[j] >> 16));
      }
#pragma unroll
      for (int e = 0; e < 4; e++) {
        la[m2][e]  = mfma16(pah, wh[e], la[m2][e]);
        lc2[m2][e] = mfma16(pal, wh[e], lc2[m2][e]);
        lc2[m2][e] = mfma16(pah, wl[e], lc2[m2][e]);
      }
    }
  }

  float* lpb = Lp + ((size_t)nblk * TOKENS + m0 + w*32) * NEXP;
#pragma unroll
  for (int m2 = 0; m2 < 2; m2++)
#pragma unroll
    for (int e = 0; e < 4; e++)
#pragma unroll
      for (int r = 0; r < 4; r++) {
        const int row = m2*16 + (i >> 4)*4 + r;
        const int col = e*16 + (i & 15);
        lpb[row*NEXP + col] = la[m2][e][r] + lc2[m2][e][r] * INV_LO_SCALE;
      }
}

// ---------------- softmax + top2 + outputs + per-expert prob sums. One wave per token.
__global__ __launch_bounds__(256) void softmax_topk_k(
    const float* __restrict__ Lp, const float* __restrict__ b2c,
    float* __restrict__ out, float* __restrict__ gloads)
{
  __shared__ float lred[4][64];
  const int tid = threadIdx.x, l = tid & 63, w = tid >> 6;
  const int tb = blockIdx.x * 16;
  const float bc = b2c[l];
  float psum = 0.0f;
#pragma unroll
  for (int it = 0; it < 4; it++) {
    const int t = tb + w*4 + it;
    const float* lp = Lp + (size_t)t * NEXP + l;
    float c = bc;
#pragma unroll
    for (int p = 0; p < NPART; p++) c += lp[(size_t)p * TOKENS * NEXP];
    float v1 = c; int i1 = l;
    for (int off = 1; off < 64; off <<= 1) {
      const float ov = __shfl_xor(v1, off);
      const int   oi = __shfl_xor(i1, off);
      if (ov > v1 || (ov == v1 && oi < i1)) { v1 = ov; i1 = oi; }
    }
    const float c2 = (l == i1) ? -3.0e38f : c;
    float v2 = c2; int i2 = l;
    for (int off = 1; off < 64; off <<= 1) {
      const float ov = __shfl_xor(v2, off);
      const int   oi = __shfl_xor(i2, off);
      if (ov > v2 || (ov == v2 && oi < i2)) { v2 = ov; i2 = oi; }
    }
    const float e = expf(c - v1);
    float Z = e;
    for (int off = 1; off < 64; off <<= 1) Z += __shfl_xor(Z, off);
    psum += e / Z;
    if (l == 0) {
      const float e2 = expf(v2 - v1);
      const float inv = 1.0f / (1.0f + e2);
      out[2*t]     = (float)i1;
      out[2*t + 1] = (float)i2;
      out[2*TOKENS + 2*t]     = inv;
      out[2*TOKENS + 2*t + 1] = e2 * inv;
    }
  }
  lred[w][l] = psum;
  __syncthreads();
  if (tid < 64)
    atomicAdd(&gloads[tid], lred[0][tid] + lred[1][tid] + lred[2][tid] + lred[3][tid]);
}

__global__ void finalize_k(const float* __restrict__ gloads, const float* __restrict__ eloads,
                           float* __restrict__ out)
{
  const int e = threadIdx.x;
  const float nl = 0.9f * eloads[e] + 0.1f * (gloads[e] * (1.0f / (float)TOKENS));
  float tot = nl;
  for (int off = 1; off < 64; off <<= 1) tot += __shfl_xor(tot, off);
  const float target = tot * (1.0f / (float)NEXP);
  const float d = nl - target;
  float aux = d * d;
  for (int off = 1; off < 64; off <<= 1) aux += __shfl_xor(aux, off);
  out[4*TOKENS + 1 + e] = nl;
  if (e == 0) out[4*TOKENS] = aux;
}

extern "C" void kernel_launch(void* const* d_in, const int* in_sizes, int n_in,
                              void* d_out, int out_size, void* d_ws, size_t ws_size,
                              hipStream_t stream)
{
  (void)in_sizes; (void)n_in; (void)out_size; (void)ws_size;
  const float* x      = (const float*)d_in[0];
  const float* gam    = (const float*)d_in[1];
  const float* bet    = (const float*)d_in[2];
  const float* w1     = (const float*)d_in[3];
  const float* b1     = (const float*)d_in[4];
  const float* w2     = (const float*)d_in[5];
  const float* b2     = (const float*)d_in[6];
  const float* lw1    = (const float*)d_in[7];
  const float* lb1    = (const float*)d_in[8];
  const float* lw2    = (const float*)d_in[9];
  const float* lb2    = (const float*)d_in[10];
  const float* eloads = (const float*)d_in[11];
  float* out = (float*)d_out;

  char* ws = (char*)d_ws;
  _Float16* xh   = (_Float16*)(ws + 0);            // 16384x2048 f16      67108864
  _Float16* xl   = (_Float16*)(ws + 67108864);     //                     67108864
  _Float16* w1th = (_Float16*)(ws + 134217728);    // 3072x2048 f16       12582912
  _Float16* w1tl = (_Float16*)(ws + 146800640);    //                     12582912
  _Float16* w2th = (_Float16*)(ws + 159383552);    // 64x3072 f16           393216
  _Float16* w2tl = (_Float16*)(ws + 159776768);    //                       393216
  float*    b1c  = (float*)   (ws + 160169984);    // 3072 f32               12288
  float*    b2c  = (float*)   (ws + 160182272);    // 64 f32                   256
  float*    Lp   = (float*)   (ws + 160182528);    // 24x16384x64 f32    100663296
  float*    gld  = (float*)   (ws + 260845824);    // 64 f32                   256

  hipMemsetAsync(gld, 0, 64 * sizeof(float), stream);

  transpose_split_k<<<dim3(64, 64), 256, 0, stream>>>(w1,  2048, 2048, 2048, w1th, w1tl, 2048, 0,    0,    1.0f);
  transpose_split_k<<<dim3(64, 32), 256, 0, stream>>>(lw1, 2048, 1024, 1024, w1th, w1tl, 2048, 2048, 0,    1.0f);
  transpose_split_k<<<dim3(64, 2),  256, 0, stream>>>(w2,  2048, 64,   64,   w2th, w2tl, 3072, 0,    0,    1.0f);
  transpose_split_k<<<dim3(32, 2),  256, 0, stream>>>(lw2, 1024, 64,   64,   w2th, w2tl, 3072, 0,    2048, 0.01f);
  prep_bias_k<<<13, 256, 0, stream>>>(b1, lb1, b2, lb2, b1c, b2c);

  ln_split_k<<<TOKENS, 256, 0, stream>>>(x, gam, bet, xh, xl);

  hipFuncSetAttribute((const void*)gemm1_fused_k,
                      hipFuncAttributeMaxDynamicSharedMemorySize, 3 * BUFB);
  gemm1_fused_k<<<1536, 512, 3 * BUFB, stream>>>(xh, xl, w1th, w1tl, w2th, w2tl, b1c, Lp);

  softmax_topk_k<<<TOKENS/16, 256, 0, stream>>>(Lp, b2c, out, gld);
  finalize_k<<<1, 64, 0, stream>>>(gld, eloads, out);
}

// Round 4
// 834.481 us; speedup vs baseline: 1.1964x; 1.0095x over previous
//
#include <hip/hip_runtime.h>
#include <hip/hip_bf16.h>
#include <stdint.h>

// EPLB router: LN -> fused [router+balance] MLP -> softmax/top2/EMA.
// Round 4: wave retile 2x4 -> 4x2 (64x64 wave tiles) to cut LDS ds_read_b128
// count/tile 160->128 (B-tile redundancy 8x->4x); phases rebalanced (8,4,4,0
// reads) so p3 reads nothing; epilogue h-transpose per row-group (wave pairs).

#define TOKENS 16384
#define HDIM   2048
#define N1     3072
#define NEXP   64
#define NPART  24            // N1/128 n-blocks -> logit partials
#define LO_SCALE 2048.0f
#define INV_LO_SCALE (1.0f/2048.0f)

typedef _Float16 half8 __attribute__((ext_vector_type(8)));
typedef float f32x4 __attribute__((ext_vector_type(4)));

__device__ __forceinline__ void gl_lds16(const void* g, void* l) {
  __builtin_amdgcn_global_load_lds((__attribute__((address_space(1))) void*)(g),
                                   (__attribute__((address_space(3))) void*)(l),
                                   16, 0, 0);
}

__device__ __forceinline__ f32x4 mfma16(half8 a, half8 b, f32x4 c) {
  return __builtin_amdgcn_mfma_f32_16x16x32_f16(a, b, c, 0, 0, 0);
}

__device__ __forceinline__ void split_f32(float v, _Float16& hi, _Float16& lo) {
  hi = (_Float16)v;
  lo = (_Float16)((v - (float)hi) * LO_SCALE);
}

// ---------------- weight transpose + split
__global__ __launch_bounds__(256) void transpose_split_k(
    const float* __restrict__ src, int R, int C, int src_ld,
    _Float16* __restrict__ dst_hi, _Float16* __restrict__ dst_lo,
    int dst_ld, int row_off, int col_off, float scale)
{
  __shared__ float tile[32][33];
  const int tx = threadIdx.x & 31, ty = threadIdx.x >> 5;
  const int r0 = blockIdx.x * 32, c0 = blockIdx.y * 32;
#pragma unroll
  for (int i = 0; i < 4; i++)
    tile[ty + i*8][tx] = src[(size_t)(r0 + ty + i*8) * src_ld + c0 + tx];
  __syncthreads();
#pragma unroll
  for (int i = 0; i < 4; i++) {
    const int c = c0 + ty + i*8;
    const int r = r0 + tx;
    const float v = tile[tx][ty + i*8] * scale;
    _Float16 h, l;
    split_f32(v, h, l);
    const size_t o = (size_t)(c + row_off) * dst_ld + (r + col_off);
    dst_hi[o] = h; dst_lo[o] = l;
  }
}

__global__ void prep_bias_k(const float* __restrict__ b1, const float* __restrict__ lb1,
                            const float* __restrict__ b2, const float* __restrict__ lb2,
                            float* __restrict__ b1c, float* __restrict__ b2c)
{
  const int i = blockIdx.x * 256 + threadIdx.x;
  if (i < 2048)      b1c[i] = b1[i];
  else if (i < 3072) b1c[i] = lb1[i - 2048];
  else if (i < 3136) { const int e = i - 3072; b2c[e] = b2[e] + 0.01f * lb2[e]; }
}

// ---------------- LayerNorm + f16 hi/lo split store
__global__ __launch_bounds__(256) void ln_split_k(
    const float* __restrict__ x, const float* __restrict__ gamma, const float* __restrict__ beta,
    _Float16* __restrict__ xh, _Float16* __restrict__ xl)
{
  const int row = blockIdx.x, tid = threadIdx.x, l = tid & 63, w = tid >> 6;
  const float* xr = x + (size_t)row * HDIM;
  const float4 v0 = ((const float4*)xr)[tid*2];
  const float4 v1 = ((const float4*)xr)[tid*2 + 1];
  float vv[8] = {v0.x, v0.y, v0.z, v0.w, v1.x, v1.y, v1.z, v1.w};
  float s = 0.0f;
#pragma unroll
  for (int j = 0; j < 8; j++) s += vv[j];
  for (int off = 1; off < 64; off <<= 1) s += __shfl_xor(s, off);
  __shared__ float r1[4], r2[4];
  if (l == 0) r1[w] = s;
  __syncthreads();
  const float mu = (r1[0] + r1[1] + r1[2] + r1[3]) * (1.0f / HDIM);
  float q = 0.0f;
#pragma unroll
  for (int j = 0; j < 8; j++) { const float d = vv[j] - mu; q += d * d; }
  for (int off = 1; off < 64; off <<= 1) q += __shfl_xor(q, off);
  if (l == 0) r2[w] = q;
  __syncthreads();
  const float var = (r2[0] + r2[1] + r2[2] + r2[3]) * (1.0f / HDIM);
  const float rsig = 1.0f / sqrtf(var + 1e-5f);
  const float4 g0 = ((const float4*)gamma)[tid*2];
  const float4 g1 = ((const float4*)gamma)[tid*2 + 1];
  const float4 be0 = ((const float4*)beta)[tid*2];
  const float4 be1 = ((const float4*)beta)[tid*2 + 1];
  const float gg[8] = {g0.x,g0.y,g0.z,g0.w,g1.x,g1.y,g1.z,g1.w};
  const float bb[8] = {be0.x,be0.y,be0.z,be0.w,be1.x,be1.y,be1.z,be1.w};
  half8 hv, lv;
#pragma unroll
  for (int j = 0; j < 8; j++) {
    const float xn = (vv[j] - mu) * rsig * gg[j] + bb[j];
    _Float16 hi, lo;
    split_f32(xn, hi, lo);
    hv[j] = hi; lv[j] = lo;
  }
  *(half8*)&xh[(size_t)row * HDIM + tid*8] = hv;
  *(half8*)&xl[(size_t)row * HDIM + tid*8] = lv;
}

// ---------------- GEMM1 fused, phased schedule, 4x2 wave grid.
// 256x128 tile, BK=32, 8 waves each 64 rows x 64 cols. 3 LDS bufs (48KB each).
// Per K-tile: 4 phases, reads (8,4,4,0), 12 MFMA each. vmcnt(6) at p3 only.
// Epilogue: relu+split -> per-row-group LDS transpose -> fused GEMM2 partials.
#define BUFB 49152

__global__ __launch_bounds__(512, 2) void gemm1_fused_k(
    const _Float16* __restrict__ xh, const _Float16* __restrict__ xl,
    const _Float16* __restrict__ w1th, const _Float16* __restrict__ w1tl,
    const _Float16* __restrict__ w2th, const _Float16* __restrict__ w2tl,
    const float* __restrict__ b1c, float* __restrict__ Lp)
{
  extern __shared__ char smem[];
  const int tid = threadIdx.x;
  const int i = tid & 63, w = tid >> 6;
  const int bid = blockIdx.x;
  // n-major XCD swizzle: XCD x owns nblk {3x..3x+2} (L2-resident W1 slice), iterates m.
  const int xcd = bid & 7, loc = bid >> 3;          // loc 0..191
  const int nblk = xcd * 3 + (loc % 3), mblk = loc / 3;
  const int m0 = mblk * 256, n0 = nblk * 128;

  const int g = w >> 1;        // row group 0..3 (64 rows each)
  const int ch = w & 1;        // col half 0..1 (64 cols each)
  const int wr = g * 64, wc = ch * 64;

  // --- staging sources: pre-swizzled global addresses, linear LDS dests
  const _Float16* srcA[4]; int ldsA[4];
  const _Float16* srcB[2]; int ldsB[2];
#pragma unroll
  for (int j = 0; j < 4; j++) {
    const int r = (w*4 + j)*8 + (i >> 3);
    const int s = (i & 7) ^ (r & 7);                 // logical slot for my phys slot
    srcA[j] = (s < 4 ? xh : xl) + (size_t)(m0 + r) * HDIM + (s & 3) * 8;
    ldsA[j] = (w*4 + j) * 1024;
  }
#pragma unroll
  for (int j = 0; j < 2; j++) {
    const int r = (w*2 + j)*8 + (i >> 3);
    const int s = (i & 7) ^ (r & 7);
    srcB[j] = (s < 4 ? w1th : w1tl) + (size_t)(n0 + r) * HDIM + (s & 3) * 8;
    ldsB[j] = 32768 + (w*2 + j) * 1024;
  }

  // --- fragment read offsets (row&7 == i&7 for all frag rows; wr/wc mult of 8)
  const int aoff = (wr + (i & 15))*128 + (((i >> 4) ^ (i & 7)) << 4);
  const int boff = 32768 + (wc + (i & 15))*128 + (((i >> 4) ^ (i & 7)) << 4);

  f32x4 am[4][4] = {{{0}}};
  f32x4 ac[4][4] = {{{0}}};

#define STG_A01(BUF, KT) { char* _b = smem + (BUF)*BUFB; \
    gl_lds16(srcA[0] + (KT), _b + ldsA[0]); \
    gl_lds16(srcA[1] + (KT), _b + ldsA[1]); }
#define STG_A23(BUF, KT) { char* _b = smem + (BUF)*BUFB; \
    gl_lds16(srcA[2] + (KT), _b + ldsA[2]); \
    gl_lds16(srcA[3] + (KT), _b + ldsA[3]); }
#define STG_B(BUF, KT) { char* _b = smem + (BUF)*BUFB; \
    gl_lds16(srcB[0] + (KT), _b + ldsB[0]); \
    gl_lds16(srcB[1] + (KT), _b + ldsB[1]); }

#define LDF(off) (*(const half8*)(bp + (off)))

#define MM3(M, N) { \
    am[M][N] = mfma16(afh[M], bfh[N], am[M][N]); \
    ac[M][N] = mfma16(afl[M], bfh[N], ac[M][N]); \
    ac[M][N] = mfma16(afh[M], bfl[N], ac[M][N]); }

// One K-tile = 4 phases; reads (8,4,4,0); p3 reads nothing (regs complete by p2).
#define TILE(BUF, SBUF, SKT, DOSTAGE, VMS) { \
    const char* bp = smem + (BUF)*BUFB; \
    half8 afh[4], afl[4], bfh[4], bfl[4]; \
    /* p0: A0,A1 + B0,B1 */ \
    afh[0] = LDF(aoff);          afl[0] = LDF(aoff ^ 64); \
    afh[1] = LDF(aoff + 2048);   afl[1] = LDF((aoff + 2048) ^ 64); \
    bfh[0] = LDF(boff);          bfl[0] = LDF(boff ^ 64); \
    bfh[1] = LDF(boff + 2048);   bfl[1] = LDF((boff + 2048) ^ 64); \
    if (DOSTAGE) STG_A01(SBUF, SKT); \
    __builtin_amdgcn_sched_barrier(0); \
    __builtin_amdgcn_s_barrier(); \
    __builtin_amdgcn_s_setprio(1); \
    MM3(0,0) MM3(0,1) MM3(1,0) MM3(1,1) \
    __builtin_amdgcn_s_setprio(0); \
    __builtin_amdgcn_sched_barrier(0); \
    /* p1: B2,B3 */ \
    bfh[2] = LDF(boff + 4096);   bfl[2] = LDF((boff + 4096) ^ 64); \
    bfh[3] = LDF(boff + 6144);   bfl[3] = LDF((boff + 6144) ^ 64); \
    if (DOSTAGE) STG_A23(SBUF, SKT); \
    __builtin_amdgcn_sched_barrier(0); \
    __builtin_amdgcn_s_barrier(); \
    __builtin_amdgcn_s_setprio(1); \
    MM3(0,2) MM3(0,3) MM3(1,2) MM3(1,3) \
    __builtin_amdgcn_s_setprio(0); \
    __builtin_amdgcn_sched_barrier(0); \
    /* p2: A2,A3 */ \
    afh[2] = LDF(aoff + 4096);   afl[2] = LDF((aoff + 4096) ^ 64); \
    afh[3] = LDF(aoff + 6144);   afl[3] = LDF((aoff + 6144) ^ 64); \
    if (DOSTAGE) STG_B(SBUF, SKT); \
    __builtin_amdgcn_sched_barrier(0); \
    __builtin_amdgcn_s_barrier(); \
    __builtin_amdgcn_s_setprio(1); \
    MM3(2,0) MM3(2,1) MM3(3,0) MM3(3,1) \
    __builtin_amdgcn_s_setprio(0); \
    __builtin_amdgcn_sched_barrier(0); \
    /* p3: no reads; counted vmcnt guarantees next tile staged */ \
    asm volatile("s_waitcnt vmcnt(" VMS ")" ::: "memory"); \
    __builtin_amdgcn_s_barrier(); \
    __builtin_amdgcn_s_setprio(1); \
    MM3(2,2) MM3(2,3) MM3(3,2) MM3(3,3) \
    __builtin_amdgcn_s_setprio(0); \
    __builtin_amdgcn_sched_barrier(0); }

  // prologue: stage tiles 0 and 1
  STG_A01(0, 0)  STG_A23(0, 0)  STG_B(0, 0)
  STG_A01(1, 32) STG_A23(1, 32) STG_B(1, 32)
  asm volatile("s_waitcnt vmcnt(6)" ::: "memory");
  __builtin_amdgcn_s_barrier();

  // main loop: t = 3u..3u+2 (t=0..59), staging t+2
  for (int u = 0; u < 20; u++) {
    const int kt = (3*u + 2) * 32;
    TILE(0, 2, kt,        1, "6")
    TILE(1, 0, kt + 32,   1, "6")
    TILE(2, 1, kt + 64,   1, "6")
  }
  TILE(0, 2, 62*32, 1, "6")   // t=60 stages 62
  TILE(1, 0, 63*32, 1, "6")   // t=61 stages 63
  TILE(2, 0, 0,     0, "0")   // t=62
  TILE(0, 0, 0,     0, "0")   // t=63
#undef TILE
#undef MM3
#undef LDF
#undef STG_A01
#undef STG_A23
#undef STG_B

  __builtin_amdgcn_s_barrier();   // K-loop LDS reads done before epilogue overwrites

  // ---- epilogue: h = relu(am + ac/2048 + b1), split, LDS transpose (packed u32).
  // Region per row-group g: 64 rows x 128 cols x 4B = 32KB at smem + g*32768.
  float bv[4];
#pragma unroll
  for (int n = 0; n < 4; n++) bv[n] = b1c[n0 + wc + n*16 + (i & 15)];

  char* hwg = smem + g * 32768;
#pragma unroll
  for (int m = 0; m < 4; m++)
#pragma unroll
    for (int n = 0; n < 4; n++)
#pragma unroll
      for (int r = 0; r < 4; r++) {
        const int lr = m*16 + (i >> 4)*4 + r;           // 0..63 within group
        const int lc = wc + n*16 + (i & 15);            // 0..127
        float v = am[m][n][r] + ac[m][n][r] * INV_LO_SCALE + bv[n];
        v = fmaxf(v, 0.0f);
        _Float16 hh, ll;
        split_f32(v, hh, ll);
        const uint32_t pk = (uint32_t)__builtin_bit_cast(unsigned short, hh) |
                            ((uint32_t)__builtin_bit_cast(unsigned short, ll) << 16);
        const int pc = lc ^ ((lr & 3) << 2) ^ (((lr >> 2) & 3) << 4);
        *(uint32_t*)(hwg + lr*512 + pc*4) = pk;
      }
  asm volatile("s_waitcnt lgkmcnt(0)" ::: "memory");
  __builtin_amdgcn_s_barrier();                         // cross-wave: pair writes both halves
  __builtin_amdgcn_sched_barrier(0);

  // ---- fused GEMM2: rows of group g (64) x K=128 vs W2c experts [ch*32, ch*32+32)
  f32x4 la[4][2] = {{{0}}};
  f32x4 lc2[4][2] = {{{0}}};
#pragma unroll
  for (int ks = 0; ks < 4; ks++) {
    half8 wh[2], wl[2];
#pragma unroll
    for (int e = 0; e < 2; e++) {
      const size_t wo = (size_t)(ch*32 + e*16 + (i & 15)) * N1 + n0 + ks*32 + ((i >> 4) << 3);
      wh[e] = *(const half8*)(w2th + wo);
      wl[e] = *(const half8*)(w2tl + wo);
    }
#pragma unroll
    for (int m2 = 0; m2 < 4; m2++) {
      const int lr = m2*16 + (i & 15);
      const int c0 = ks*32 + ((i >> 4) << 3);
      const int x1 = ((lr & 3) << 2) ^ (((lr >> 2) & 3) << 4);
      const uint4 cl0 = *(const uint4*)(hwg + lr*512 + ((c0 ^ x1) << 2));
      const uint4 cl1 = *(const uint4*)(hwg + lr*512 + (((c0 + 4) ^ x1) << 2));
      const uint32_t cu[8] = {cl0.x, cl0.y, cl0.z, cl0.w, cl1.x, cl1.y, cl1.z, cl1.w};
      half8 pah, pal;
#pragma unroll
      for (int j = 0; j < 8; j++) {
        pah[j] = __builtin_bit_cast(_Float16, (unsigned short)(cu[j] & 0xffff));
        pal[j] = __builtin_bit_cast(_Float16, (unsigned short)(cu[j] >> 16));
      }
#pragma unroll
      for (int e = 0; e < 2; e++) {
        la[m2][e]  = mfma16(pah, wh[e], la[m2][e]);
        lc2[m2][e] = mfma16(pal, wh[e], lc2[m2][e]);
        lc2[m2][e] = mfma16(pah, wl[e], lc2[m2][e]);
      }
    }
  }

  float* lpb = Lp + ((size_t)nblk * TOKENS + m0 + wr) * NEXP;
#pragma unroll
  for (int m2 = 0; m2 < 4; m2++)
#pragma unroll
    for (int e = 0; e < 2; e++)
#pragma unroll
      for (int r = 0; r < 4; r++) {
        const int row = m2*16 + (i >> 4)*4 + r;
        const int col = ch*32 + e*16 + (i & 15);
        lpb[row*NEXP + col] = la[m2][e][r] + lc2[m2][e][r] * INV_LO_SCALE;
      }
}

// ---------------- softmax + top2 + outputs + per-expert prob sums. One wave per token.
__global__ __launch_bounds__(256) void softmax_topk_k(
    const float* __restrict__ Lp, const float* __restrict__ b2c,
    float* __restrict__ out, float* __restrict__ gloads)
{
  __shared__ float lred[4][64];
  const int tid = threadIdx.x, l = tid & 63, w = tid >> 6;
  const int tb = blockIdx.x * 16;
  const float bc = b2c[l];
  float psum = 0.0f;
#pragma unroll
  for (int it = 0; it < 4; it++) {
    const int t = tb + w*4 + it;
    const float* lp = Lp + (size_t)t * NEXP + l;
    float c = bc;
#pragma unroll
    for (int p = 0; p < NPART; p++) c += lp[(size_t)p * TOKENS * NEXP];
    float v1 = c; int i1 = l;
    for (int off = 1; off < 64; off <<= 1) {
      const float ov = __shfl_xor(v1, off);
      const int   oi = __shfl_xor(i1, off);
      if (ov > v1 || (ov == v1 && oi < i1)) { v1 = ov; i1 = oi; }
    }
    const float c2 = (l == i1) ? -3.0e38f : c;
    float v2 = c2; int i2 = l;
    for (int off = 1; off < 64; off <<= 1) {
      const float ov = __shfl_xor(v2, off);
      const int   oi = __shfl_xor(i2, off);
      if (ov > v2 || (ov == v2 && oi < i2)) { v2 = ov; i2 = oi; }
    }
    const float e = expf(c - v1);
    float Z = e;
    for (int off = 1; off < 64; off <<= 1) Z += __shfl_xor(Z, off);
    psum += e / Z;
    if (l == 0) {
      const float e2 = expf(v2 - v1);
      const float inv = 1.0f / (1.0f + e2);
      out[2*t]     = (float)i1;
      out[2*t + 1] = (float)i2;
      out[2*TOKENS + 2*t]     = inv;
      out[2*TOKENS + 2*t + 1] = e2 * inv;
    }
  }
  lred[w][l] = psum;
  __syncthreads();
  if (tid < 64)
    atomicAdd(&gloads[tid], lred[0][tid] + lred[1][tid] + lred[2][tid] + lred[3][tid]);
}

__global__ void finalize_k(const float* __restrict__ gloads, const float* __restrict__ eloads,
                           float* __restrict__ out)
{
  const int e = threadIdx.x;
  const float nl = 0.9f * eloads[e] + 0.1f * (gloads[e] * (1.0f / (float)TOKENS));
  float tot = nl;
  for (int off = 1; off < 64; off <<= 1) tot += __shfl_xor(tot, off);
  const float target = tot * (1.0f / (float)NEXP);
  const float d = nl - target;
  float aux = d * d;
  for (int off = 1; off < 64; off <<= 1) aux += __shfl_xor(aux, off);
  out[4*TOKENS + 1 + e] = nl;
  if (e == 0) out[4*TOKENS] = aux;
}

extern "C" void kernel_launch(void* const* d_in, const int* in_sizes, int n_in,
                              void* d_out, int out_size, void* d_ws, size_t ws_size,
                              hipStream_t stream)
{
  (void)in_sizes; (void)n_in; (void)out_size; (void)ws_size;
  const float* x      = (const float*)d_in[0];
  const float* gam    = (const float*)d_in[1];
  const float* bet    = (const float*)d_in[2];
  const float* w1     = (const float*)d_in[3];
  const float* b1     = (const float*)d_in[4];
  const float* w2     = (const float*)d_in[5];
  const float* b2     = (const float*)d_in[6];
  const float* lw1    = (const float*)d_in[7];
  const float* lb1    = (const float*)d_in[8];
  const float* lw2    = (const float*)d_in[9];
  const float* lb2    = (const float*)d_in[10];
  const float* eloads = (const float*)d_in[11];
  float* out = (float*)d_out;

  char* ws = (char*)d_ws;
  _Float16* xh   = (_Float16*)(ws + 0);            // 16384x2048 f16      67108864
  _Float16* xl   = (_Float16*)(ws + 67108864);     //                     67108864
  _Float16* w1th = (_Float16*)(ws + 134217728);    // 3072x2048 f16       12582912
  _Float16* w1tl = (_Float16*)(ws + 146800640);    //                     12582912
  _Float16* w2th = (_Float16*)(ws + 159383552);    // 64x3072 f16           393216
  _Float16* w2tl = (_Float16*)(ws + 159776768);    //                       393216
  float*    b1c  = (float*)   (ws + 160169984);    // 3072 f32               12288
  float*    b2c  = (float*)   (ws + 160182272);    // 64 f32                   256
  float*    Lp   = (float*)   (ws + 160182528);    // 24x16384x64 f32    100663296
  float*    gld  = (float*)   (ws + 260845824);    // 64 f32                   256

  hipMemsetAsync(gld, 0, 64 * sizeof(float), stream);

  transpose_split_k<<<dim3(64, 64), 256, 0, stream>>>(w1,  2048, 2048, 2048, w1th, w1tl, 2048, 0,    0,    1.0f);
  transpose_split_k<<<dim3(64, 32), 256, 0, stream>>>(lw1, 2048, 1024, 1024, w1th, w1tl, 2048, 2048, 0,    1.0f);
  transpose_split_k<<<dim3(64, 2),  256, 0, stream>>>(w2,  2048, 64,   64,   w2th, w2tl, 3072, 0,    0,    1.0f);
  transpose_split_k<<<dim3(32, 2),  256, 0, stream>>>(lw2, 1024, 64,   64,   w2th, w2tl, 3072, 0,    2048, 0.01f);
  prep_bias_k<<<13, 256, 0, stream>>>(b1, lb1, b2, lb2, b1c, b2c);

  ln_split_k<<<TOKENS, 256, 0, stream>>>(x, gam, bet, xh, xl);

  hipFuncSetAttribute((const void*)gemm1_fused_k,
                      hipFuncAttributeMaxDynamicSharedMemorySize, 3 * BUFB);
  gemm1_fused_k<<<1536, 512, 3 * BUFB, stream>>>(xh, xl, w1th, w1tl, w2th, w2tl, b1c, Lp);

  softmax_topk_k<<<TOKENS/16, 256, 0, stream>>>(Lp, b2c, out, gld);
  finalize_k<<<1, 64, 0, stream>>>(gld, eloads, out);
}